// Round 9
// baseline (83.749 us; speedup 1.0000x reference)
//
#include <hip/hip_runtime.h>
#include <math.h>

#define M_BATCH 8
#define NC 1024
#define NTGT 512
#define G_DIM 129
#define NG (G_DIM * G_DIM)        // 16641
#define N_OUT (G_DIM * 3)         // 387
#define MT_TILES 9                // ceil(129/16)
#define NT_TILES 25               // ceil(387/16)
#define SPLIT 4                   // waves per block = K-splits
#define KSP (NC / SPLIT)          // 256

typedef __attribute__((ext_vector_type(8))) _Float16 half8;
typedef __attribute__((ext_vector_type(4))) float floatx4;

#if defined(__has_builtin)
#if __has_builtin(__builtin_amdgcn_exp2f)
#define FAST_EXP2(x) __builtin_amdgcn_exp2f(x)
#endif
#endif
#ifndef FAST_EXP2
#define FAST_EXP2(x) exp2f(x)
#endif

// One kernel. Block = one 16x16 (ix x n) output tile of batch m; its 4 waves
// are 4 K-splits of 256 ctx points each. MFMA fragments are computed DIRECTLY
// in registers (A[row=lane&15][k=quad*8+j]) from float4 xc/yc loads — no LDS
// staging, no per-chunk barriers. Cross-wave K-reduction via one 4KB LDS
// stage + single barrier.
__global__ __launch_bounds__(256, 7) void fused_kernel(
        const float* __restrict__ xc, const float* __restrict__ yc,
        const float* __restrict__ xt, const float* __restrict__ lsp,
        float* __restrict__ out_grid, float* __restrict__ out_z) {
    const int tid = threadIdx.x;
    const int t = blockIdx.x;              // 0..224
    const int m = blockIdx.y;
    const int mt = t / NT_TILES;
    const int nt = t - mt * NT_TILES;

    __shared__ float4 sm[256];
    __shared__ floatx4 cs[SPLIT][64];

    // ---- Phase 1: minmax over concat(xc[m], xt[m]) ----
    float mn0 = 1e30f, mx0 = -1e30f, mn1 = 1e30f, mx1 = -1e30f;
    const float2* pc = (const float2*)(xc + m * NC * 2);
    for (int i = tid; i < NC; i += 256) {
        float2 p = pc[i];
        mn0 = fminf(mn0, p.x); mx0 = fmaxf(mx0, p.x);
        mn1 = fminf(mn1, p.y); mx1 = fmaxf(mx1, p.y);
    }
    const float2* pt = (const float2*)(xt + m * NTGT * 2);
    for (int i = tid; i < NTGT; i += 256) {
        float2 p = pt[i];
        mn0 = fminf(mn0, p.x); mx0 = fmaxf(mx0, p.x);
        mn1 = fminf(mn1, p.y); mx1 = fmaxf(mx1, p.y);
    }
    sm[tid] = make_float4(mn0, mx0, mn1, mx1);
    __syncthreads();
    for (int s = 128; s > 0; s >>= 1) {
        if (tid < s) {
            float4 a = sm[tid], b = sm[tid + s];
            sm[tid] = make_float4(fminf(a.x, b.x), fmaxf(a.y, b.y),
                                  fminf(a.z, b.z), fmaxf(a.w, b.w));
        }
        __syncthreads();
    }
    const float mid0 = 0.5f * (sm[0].x + sm[0].y);
    const float mid1 = 0.5f * (sm[0].z + sm[0].w);

    // w = exp(-0.5*((dx/ls0)^2+(dy/ls1)^2)) = exp2(-((K*dx/ls0)^2+(K*dy/ls1)^2))
    const float Kc = 0.84932180028801904272f;  // sqrt(0.5*log2(e))
    const float ls0 = 1e-5f + log1pf(expf(lsp[0]));
    const float ls1 = 1e-5f + log1pf(expf(lsp[1]));
    const float s0 = Kc / ls0, s1 = Kc / ls1;
    const float inv_ppu = 1.0f / 64.0f;

    // ---- Phase 2: x_grid rows of this mt (nt==0 blocks) ----
    if (nt == 0) {
        const int r0 = mt * 16;
        const int nrows = min(16, G_DIM - r0);
        float2* og = (float2*)out_grid + (size_t)m * NG;
        for (int g = tid; g < nrows * G_DIM; g += 256) {
            const int r = g / G_DIM;
            const int iyy = g - r * G_DIM;
            const int ixg = r0 + r;
            og[(size_t)ixg * G_DIM + iyy] =
                make_float2(mid0 + (float)(ixg - 64) * inv_ppu,
                            mid1 + (float)(iyy - 64) * inv_ppu);
        }
    }

    // ---- Phase 3: register-fragment MFMA over this wave's K-split ----
    const int w = tid >> 6;            // split id 0..3
    const int lane = tid & 63;
    const int ln = lane & 15;
    const int q = lane >> 4;

    const int ixg = mt * 16 + ln;      // A row (may exceed 128; masked at store)
    const int ng0 = nt * 16 + ln;      // B row = n index
    const int iy = ng0 / 3;
    const int ch = ng0 - 3 * iy;

    const float gxs = (mid0 + (float)(ixg - 64) * inv_ppu) * s0;
    const float gys = (mid1 + (float)(iy - 64) * inv_ppu) * s1;

    const float4* xc4 = (const float4*)(xc + m * NC * 2);  // [pair]=cx0,cy0,cx1,cy1
    const float4* yc4 = (const float4*)(yc + m * NC * 2);  // [pair]=y00,y01,y10,y11

    floatx4 acc = {0.f, 0.f, 0.f, 0.f};
    const int pbase = w * (KSP / 2) + q * 4;   // float4-pair index for this lane

    for (int kk = 0; kk < KSP / 32; ++kk) {    // 8 k-steps of 32
        const int p = pbase + kk * 16;
        half8 a, b;
#pragma unroll
        for (int h = 0; h < 2; ++h) {          // two 4-element halves (reg pressure)
            const float4 x0 = xc4[p + 2 * h + 0];
            const float4 x1 = xc4[p + 2 * h + 1];
            const float4 y0 = yc4[p + 2 * h + 0];
            const float4 y1 = yc4[p + 2 * h + 1];
            const float cxs[4] = {x0.x, x0.z, x1.x, x1.z};
            const float cys[4] = {x0.y, x0.w, x1.y, x1.w};
            const float ye[4]  = {y0.x, y0.z, y1.x, y1.z};
            const float yo[4]  = {y0.y, y0.w, y1.y, y1.w};
#pragma unroll
            for (int j = 0; j < 4; ++j) {
                const float dx = fmaf(-cxs[j], s0, gxs);
                a[4 * h + j] = (_Float16)FAST_EXP2(-(dx * dx));
                const float dy = fmaf(-cys[j], s1, gys);
                const float wy = FAST_EXP2(-(dy * dy));
                const float yv = (ch == 0) ? ye[j] : (ch == 1) ? yo[j] : 1.0f;
                b[4 * h + j] = (_Float16)(wy * yv);
            }
        }
        acc = __builtin_amdgcn_mfma_f32_16x16x32_f16(a, b, acc, 0, 0, 0);
    }

    // ---- Phase 4: cross-wave K-reduction in LDS, masked store ----
    cs[w][lane] = acc;
    __syncthreads();

    const int cl = tid & 15;           // col within tile
    const int r = tid >> 4;            // row within tile 0..15
    const int lsrc = (r >> 2) * 16 + cl;
    const int rr = r & 3;
    float v = ((const float*)&cs[0][lsrc])[rr]
            + ((const float*)&cs[1][lsrc])[rr]
            + ((const float*)&cs[2][lsrc])[rr]
            + ((const float*)&cs[3][lsrc])[rr];

    const int ixo = mt * 16 + r;
    const int ngo = nt * 16 + cl;
    if (ixo < G_DIM && ngo < N_OUT)
        out_z[(size_t)m * NG * 3 + (size_t)ixo * N_OUT + ngo] = v;
}

extern "C" void kernel_launch(void* const* d_in, const int* in_sizes, int n_in,
                              void* d_out, int out_size, void* d_ws, size_t ws_size,
                              hipStream_t stream) {
    const float* xc  = (const float*)d_in[0];
    const float* yc  = (const float*)d_in[1];
    const float* xt  = (const float*)d_in[2];
    const float* lsp = (const float*)d_in[3];

    float* out_grid = (float*)d_out;
    float* out_z = out_grid + (size_t)M_BATCH * NG * 2;

    dim3 grid(MT_TILES * NT_TILES, M_BATCH);   // (225, 8) = 1800 blocks
    fused_kernel<<<grid, 256, 0, stream>>>(xc, yc, xt, lsp, out_grid, out_z);
}

// Round 11
// 73.242 us; speedup vs baseline: 1.1435x; 1.1435x over previous
//
#include <hip/hip_runtime.h>
#include <math.h>

#define M_BATCH 8
#define NC 1024
#define NTGT 512
#define G_DIM 129
#define NG (G_DIM * G_DIM)        // 16641
#define N_OUT (G_DIM * 3)         // 387
#define TM 32
#define TN 32
#define KCH 128                   // ctx per LDS chunk
#define NKCH (NC / KCH)           // 8
#define LDA 136                   // padded row stride in halves (272 B = 17*16)
#define MT_TILES 5                // ceil(129/32)
#define NT_TILES 13               // ceil(387/32)
#define ABYTES (TM * LDA * 2)     // 8704 B per A (or B) tile

typedef __attribute__((ext_vector_type(8))) _Float16 half8;
typedef __attribute__((ext_vector_type(2))) _Float16 half2v;
typedef __attribute__((ext_vector_type(4))) float floatx4;

#if defined(__has_builtin)
#if __has_builtin(__builtin_amdgcn_exp2f)
#define FAST_EXP2(x) __builtin_amdgcn_exp2f(x)
#endif
#endif
#ifndef FAST_EXP2
#define FAST_EXP2(x) exp2f(x)
#endif

// One fused kernel. Block = 32x32 (ix x n) tile of batch m; 512 threads =
// 8 waves = 2x2 subtiles x 2 K-groups (each group takes half of every staged
// K=128 chunk). Double-buffered LDS staging, 1 barrier per chunk. Cross-group
// K-reduction via 4KB LDS at the end. LDS pointers derived from integer
// offsets only (no pointer arrays -> no addrspacecast static init).
__global__ __launch_bounds__(512) void fused_kernel(
        const float* __restrict__ xc, const float* __restrict__ yc,
        const float* __restrict__ xt, const float* __restrict__ lsp,
        float* __restrict__ out_grid, float* __restrict__ out_z) {
    const int tid = threadIdx.x;
    const int t = blockIdx.x;              // 0..64
    const int m = blockIdx.y;
    const int mt = t / NT_TILES;
    const int nt = t - mt * NT_TILES;

    // Overlaid LDS: [minmax sm 8KB | cs 4KB] / [A0 B0 A1 B1 = 34816B]
    __shared__ __align__(16) char lds_raw[4 * ABYTES];

    // ---- Phase 1: minmax over concat(xc[m], xt[m]) ----
    {
        float mn0 = 1e30f, mx0 = -1e30f, mn1 = 1e30f, mx1 = -1e30f;
        const float2* pc = (const float2*)(xc + m * NC * 2);
        for (int i = tid; i < NC; i += 512) {
            float2 p = pc[i];
            mn0 = fminf(mn0, p.x); mx0 = fmaxf(mx0, p.x);
            mn1 = fminf(mn1, p.y); mx1 = fmaxf(mx1, p.y);
        }
        const float2* pt = (const float2*)(xt + m * NTGT * 2);
        {
            float2 p = pt[tid];
            mn0 = fminf(mn0, p.x); mx0 = fmaxf(mx0, p.x);
            mn1 = fminf(mn1, p.y); mx1 = fmaxf(mx1, p.y);
        }
        float4* sm = (float4*)lds_raw;
        sm[tid] = make_float4(mn0, mx0, mn1, mx1);
    }
    __syncthreads();
    {
        float4* sm = (float4*)lds_raw;
        for (int s = 256; s > 0; s >>= 1) {
            if (tid < s) {
                float4 a = sm[tid], b = sm[tid + s];
                sm[tid] = make_float4(fminf(a.x, b.x), fmaxf(a.y, b.y),
                                      fminf(a.z, b.z), fmaxf(a.w, b.w));
            }
            __syncthreads();
        }
    }
    const float mid0 = 0.5f * (((float4*)lds_raw)[0].x + ((float4*)lds_raw)[0].y);
    const float mid1 = 0.5f * (((float4*)lds_raw)[0].z + ((float4*)lds_raw)[0].w);
    __syncthreads();   // before LDS reuse for A/B staging

    const float Kc = 0.84932180028801904272f;  // sqrt(0.5*log2(e))
    const float ls0 = 1e-5f + log1pf(expf(lsp[0]));
    const float ls1 = 1e-5f + log1pf(expf(lsp[1]));
    const float s0 = Kc / ls0, s1 = Kc / ls1;
    const float inv_ppu = 1.0f / 64.0f;

    // ---- Phase 2: x_grid rows of this mt (nt==0 blocks) ----
    if (nt == 0) {
        const int r0 = mt * TM;
        const int nrows = min(TM, G_DIM - r0);
        float2* og = (float2*)out_grid + (size_t)m * NG;
        for (int g = tid; g < nrows * G_DIM; g += 512) {
            const int r = g / G_DIM;
            const int iyy = g - r * G_DIM;
            const int ixg = r0 + r;
            og[(size_t)ixg * G_DIM + iyy] =
                make_float2(mid0 + (float)(ixg - 64) * inv_ppu,
                            mid1 + (float)(iyy - 64) * inv_ppu);
        }
    }

    // ---- staging setup: thread -> (c-pair, 4 row-slots) ----
    const int c2 = (tid & 63) * 2;        // local c pair 0..126
    const int r0s = tid >> 6;             // row slot base 0..7 (rows r0s+8i)
    const float4* xc4 = (const float4*)(xc + m * NC * 2);
    const float4* yc4 = (const float4*)(yc + m * NC * 2);
    const float gxs_base = (mid0 + (float)(mt * TM - 64) * inv_ppu) * s0;
    const float gstep = inv_ppu * s0;

    // ---- MFMA mapping: 8 waves = (g, wm, wn) ----
    const int w = tid >> 6;
    const int g = w >> 2;                 // K-group 0/1
    const int wm = (w >> 1) & 1;
    const int wn = w & 1;
    const int lane = tid & 63;
    const int ln = lane & 15;
    const int q = lane >> 4;

    floatx4 acc = {0.f, 0.f, 0.f, 0.f};

    // stage one chunk into buffer buf (0/1)
    auto stage = [&](int kc, int buf) {
        const int cp = (kc * KCH >> 1) + (tid & 63);   // float4-pair index
        const float4 xq = xc4[cp];
        const float4 yq = yc4[cp];
        const float cx0 = xq.x * s0, cx1 = xq.z * s0;
        const float cy0 = xq.y * s1, cy1 = xq.w * s1;
        _Float16* Ab = (_Float16*)(lds_raw + (size_t)buf * 2 * ABYTES);
        _Float16* Bb = (_Float16*)(lds_raw + (size_t)buf * 2 * ABYTES + ABYTES);
#pragma unroll
        for (int i = 0; i < 4; ++i) {
            const int r = r0s + 8 * i;
            // A row r
            const float gxs = gxs_base + (float)r * gstep;
            const float dx0 = gxs - cx0;
            const float dx1 = gxs - cx1;
            *(half2v*)&Ab[r * LDA + c2] =
                (half2v){(_Float16)FAST_EXP2(-(dx0 * dx0)),
                         (_Float16)FAST_EXP2(-(dx1 * dx1))};
            // B row r: n = nt*32 + r
            const int n = nt * TN + r;
            const int iy = (int)(((unsigned)n * 0xAAABu) >> 17);
            const int ch = n - 3 * iy;
            const float gys = (mid1 + (float)(iy - 64) * inv_ppu) * s1;
            const float dy0 = gys - cy0;
            const float dy1 = gys - cy1;
            const float wy0 = FAST_EXP2(-(dy0 * dy0));
            const float wy1 = FAST_EXP2(-(dy1 * dy1));
            const float ya = (ch == 0) ? yq.x : (ch == 1) ? yq.y : 1.0f;
            const float yb = (ch == 0) ? yq.z : (ch == 1) ? yq.w : 1.0f;
            *(half2v*)&Bb[r * LDA + c2] =
                (half2v){(_Float16)(wy0 * ya), (_Float16)(wy1 * yb)};
        }
    };

    stage(0, 0);
    __syncthreads();

    for (int kc = 0; kc < NKCH; ++kc) {
        const int buf = kc & 1;
        const _Float16* Ab = (const _Float16*)(lds_raw + (size_t)buf * 2 * ABYTES);
        const _Float16* Bb = (const _Float16*)(lds_raw + (size_t)buf * 2 * ABYTES + ABYTES);
        // this wave's K-half of the staged chunk: local k in [g*64, g*64+64)
#pragma unroll
        for (int kk = 0; kk < 2; ++kk) {
            half8 a = *(const half8*)&Ab[(wm * 16 + ln) * LDA + g * 64 + kk * 32 + q * 8];
            half8 b = *(const half8*)&Bb[(wn * 16 + ln) * LDA + g * 64 + kk * 32 + q * 8];
            acc = __builtin_amdgcn_mfma_f32_16x16x32_f16(a, b, acc, 0, 0, 0);
        }
        if (kc + 1 < NKCH) stage(kc + 1, buf ^ 1);
        __syncthreads();
    }

    // ---- cross-group K-reduction (group1 -> LDS, group0 adds) + store ----
    floatx4* cs = (floatx4*)lds_raw;       // [4][64]
    if (g == 1) cs[(size_t)(w & 3) * 64 + lane] = acc;
    __syncthreads();
    if (g == 0) {
        const floatx4 o = cs[(size_t)w * 64 + lane];
        const int ngo = nt * TN + wn * 16 + ln;
        if (ngo < N_OUT) {
            float* oz = out_z + (size_t)m * NG * 3;
            const int ixb = mt * TM + wm * 16 + q * 4;
#pragma unroll
            for (int rr = 0; rr < 4; ++rr) {
                const int ixg = ixb + rr;
                if (ixg < G_DIM)
                    oz[(size_t)ixg * N_OUT + ngo] = acc[rr] + o[rr];
            }
        }
    }
}

extern "C" void kernel_launch(void* const* d_in, const int* in_sizes, int n_in,
                              void* d_out, int out_size, void* d_ws, size_t ws_size,
                              hipStream_t stream) {
    const float* xc  = (const float*)d_in[0];
    const float* yc  = (const float*)d_in[1];
    const float* xt  = (const float*)d_in[2];
    const float* lsp = (const float*)d_in[3];

    float* out_grid = (float*)d_out;
    float* out_z = out_grid + (size_t)M_BATCH * NG * 2;

    dim3 grid(MT_TILES * NT_TILES, M_BATCH);   // (65, 8) = 520 blocks x 512 thr
    fused_kernel<<<grid, 512, 0, stream>>>(xc, yc, xt, lsp, out_grid, out_z);
}